// Round 5
// baseline (112.775 us; speedup 1.0000x reference)
//
#include <hip/hip_runtime.h>

// BaseHashCode: per-row prefix hash of 64 int digits.
//   prefix_ids[r][t] = ((sum_{i<=t} a[i]*x[r][i] + b) % 1000003) % 65536
//   positions t >= len(r) (len = #nonzero digits) take prefix_ids[(len-1) mod 64].
// Mapping: one row per 16-lane group (== one DPP "row"); each lane owns 4
// consecutive digits via a 16B vector load. All cross-lane traffic via DPP
// (VALU cost, zero DS ops). Streaming loads/stores nontemporal.
// Software-pipelined: next group's 4 loads issue BEFORE current group's
// compute, so 4 loads stay in flight through the ~500-cycle compute+store
// phase (the compiler emits s_waitcnt vmcnt(4), not vmcnt(0)).
// All arithmetic fits int32 (max cumsum < 2^29), matching JAX int32 semantics.

constexpr int PRIME = 1000003;

typedef int vint4 __attribute__((ext_vector_type(4)));

template <int CTRL>
__device__ __forceinline__ int dpp_mov(int v) {
    // old=0, row_mask=0xF, bank_mask=0xF, bound_ctrl=true (invalid lanes -> 0)
    return __builtin_amdgcn_update_dpp(0, v, CTRL, 0xF, 0xF, true);
}

__device__ __forceinline__ vint4 process_chunk(vint4 x, vint4 av, int b, int j) {
    // per-lane products and local inclusive prefix
    int p0 = av.x * x.x;
    int p1 = av.y * x.y;
    int p2 = av.z * x.z;
    int p3 = av.w * x.w;
    int l1 = p0 + p1;
    int l2 = l1 + p2;
    int l3 = l2 + p3;   // lane total

    // 16-lane inclusive scan of lane totals (DPP row_shr, zero-fill)
    int v = l3;
    v += dpp_mov<0x111>(v);   // row_shr:1
    v += dpp_mov<0x112>(v);   // row_shr:2
    v += dpp_mov<0x114>(v);   // row_shr:4
    v += dpp_mov<0x118>(v);   // row_shr:8
    int excl = v - l3;

    int pid0 = ((excl + p0 + b) % PRIME) & 65535;
    int pid1 = ((excl + l1 + b) % PRIME) & 65535;
    int pid2 = ((excl + l2 + b) % PRIME) & 65535;
    int pid3 = ((excl + l3 + b) % PRIME) & 65535;

    // row length = count of nonzero digits; row_ror butterfly -> all lanes
    int cnt = (x.x != 0) + (x.y != 0) + (x.z != 0) + (x.w != 0);
    cnt += dpp_mov<0x128>(cnt);   // row_ror:8
    cnt += dpp_mov<0x124>(cnt);   // row_ror:4
    cnt += dpp_mov<0x122>(cnt);   // row_ror:2
    cnt += dpp_mov<0x121>(cnt);   // row_ror:1

    // broadcast prefix_ids[(cnt-1) mod 64]: zero non-owner, add-reduce
    int g     = (cnt == 0) ? 63 : (cnt - 1);   // JAX: (-1) % 64 == 63
    int slot  = g & 3;                          // row-uniform
    int owner = g >> 2;                         // lane-in-group holding it
    int sel   = (slot == 0) ? pid0 : (slot == 1) ? pid1
              : (slot == 2) ? pid2 : pid3;
    int last  = (j == owner) ? sel : 0;
    last += dpp_mov<0x128>(last);
    last += dpp_mov<0x124>(last);
    last += dpp_mov<0x122>(last);
    last += dpp_mov<0x121>(last);

    int base_pos = j << 2;
    vint4 o;
    o.x = (base_pos + 0 < cnt) ? pid0 : last;
    o.y = (base_pos + 1 < cnt) ? pid1 : last;
    o.z = (base_pos + 2 < cnt) ? pid2 : last;
    o.w = (base_pos + 3 < cnt) ? pid3 : last;
    return o;
}

__global__ __launch_bounds__(256) void BaseHashCode_kernel(
    const vint4* __restrict__ seq4,  // [rows*16] vint4 view of [rows][64] int32
    const int*   __restrict__ a,     // [64]
    const int*   __restrict__ bptr,  // [1]
    vint4* __restrict__ out4,        // [rows*16]
    int total_chunks)                // rows*16
{
    const int lane = threadIdx.x & 63;
    const int j    = lane & 15;          // lane within 16-lane row group
    const int b    = bptr[0];
    const vint4 av = reinterpret_cast<const vint4*>(a)[j];  // a[4j..4j+3]

    const int stride = gridDim.x * blockDim.x;
    const int step   = 4 * stride;
    int chunk = blockIdx.x * blockDim.x + threadIdx.x;

    // Software-pipelined 4x-unrolled grid-stride loop. stride % 16 == 0 and
    // total_chunks % 16 == 0 -> all guards are uniform within each 16-lane
    // group, so DPP lane patterns stay intact.
    if (chunk + 3 * stride < total_chunks) {
        // prologue: load group 0
        vint4 x0 = __builtin_nontemporal_load(&seq4[chunk]);
        vint4 x1 = __builtin_nontemporal_load(&seq4[chunk + stride]);
        vint4 x2 = __builtin_nontemporal_load(&seq4[chunk + 2 * stride]);
        vint4 x3 = __builtin_nontemporal_load(&seq4[chunk + 3 * stride]);

        int next = chunk + step;
        while (next + 3 * stride < total_chunks) {
            // prefetch next group BEFORE touching x0..x3 (keeps 4 loads in
            // flight across the compute phase: waitcnt vmcnt(4), not 0)
            vint4 y0 = __builtin_nontemporal_load(&seq4[next]);
            vint4 y1 = __builtin_nontemporal_load(&seq4[next + stride]);
            vint4 y2 = __builtin_nontemporal_load(&seq4[next + 2 * stride]);
            vint4 y3 = __builtin_nontemporal_load(&seq4[next + 3 * stride]);

            vint4 o0 = process_chunk(x0, av, b, j);
            vint4 o1 = process_chunk(x1, av, b, j);
            vint4 o2 = process_chunk(x2, av, b, j);
            vint4 o3 = process_chunk(x3, av, b, j);
            __builtin_nontemporal_store(o0, &out4[chunk]);
            __builtin_nontemporal_store(o1, &out4[chunk + stride]);
            __builtin_nontemporal_store(o2, &out4[chunk + 2 * stride]);
            __builtin_nontemporal_store(o3, &out4[chunk + 3 * stride]);

            x0 = y0; x1 = y1; x2 = y2; x3 = y3;
            chunk = next;
            next += step;
        }
        // epilogue: drain the last full group
        vint4 o0 = process_chunk(x0, av, b, j);
        vint4 o1 = process_chunk(x1, av, b, j);
        vint4 o2 = process_chunk(x2, av, b, j);
        vint4 o3 = process_chunk(x3, av, b, j);
        __builtin_nontemporal_store(o0, &out4[chunk]);
        __builtin_nontemporal_store(o1, &out4[chunk + stride]);
        __builtin_nontemporal_store(o2, &out4[chunk + 2 * stride]);
        __builtin_nontemporal_store(o3, &out4[chunk + 3 * stride]);
        chunk += step;
    }
    // remainder (empty at the shipped grid: 32 chunks/thread exactly)
    for (; chunk < total_chunks; chunk += stride) {
        vint4 x = __builtin_nontemporal_load(&seq4[chunk]);
        vint4 o = process_chunk(x, av, b, j);
        __builtin_nontemporal_store(o, &out4[chunk]);
    }
}

extern "C" void kernel_launch(void* const* d_in, const int* in_sizes, int n_in,
                              void* d_out, int out_size, void* d_ws, size_t ws_size,
                              hipStream_t stream) {
    const vint4* seq4 = reinterpret_cast<const vint4*>(d_in[0]);
    const int*   a    = reinterpret_cast<const int*>(d_in[1]);
    const int*   bptr = reinterpret_cast<const int*>(d_in[2]);
    vint4*       out4 = reinterpret_cast<vint4*>(d_out);

    const int total_chunks = in_sizes[0] / 4;   // rows*16 vint4 chunks

    const int threads = 256;
    const int blocks  = 2048;   // 8 blocks/CU (max resident), grid-stride
    hipLaunchKernelGGL(BaseHashCode_kernel, dim3(blocks), dim3(threads), 0, stream,
                       seq4, a, bptr, out4, total_chunks);
}

// Round 6
// 93.413 us; speedup vs baseline: 1.2073x; 1.2073x over previous
//
#include <hip/hip_runtime.h>

// BaseHashCode: per-row prefix hash of 64 int digits.
//   prefix_ids[r][t] = ((sum_{i<=t} a[i]*x[r][i] + b) % 1000003) % 65536
//   positions t >= len(r) (len = #nonzero digits) take prefix_ids[(len-1) mod 64].
// Mapping: one row per 16-lane group (== one DPP "row"); each lane owns 4
// consecutive digits via a 16B vector load. All cross-lane traffic via DPP
// (VALU cost, zero DS ops). Streaming loads/stores nontemporal.
// Each WAVE owns a contiguous 4KB tile (4 adjacent 1KB bursts) per outer
// iteration -> DRAM row-buffer-local streams, 4x fewer distinct streams than
// the strided-unroll layout. No hand pipelining (R5 showed it defeats the
// compiler's scheduler: 101.7 -> 112.8 us).
// All arithmetic fits int32 (max cumsum < 2^29), matching JAX int32 semantics.

constexpr int PRIME = 1000003;

typedef int vint4 __attribute__((ext_vector_type(4)));

template <int CTRL>
__device__ __forceinline__ int dpp_mov(int v) {
    // old=0, row_mask=0xF, bank_mask=0xF, bound_ctrl=true (invalid lanes -> 0)
    return __builtin_amdgcn_update_dpp(0, v, CTRL, 0xF, 0xF, true);
}

__device__ __forceinline__ vint4 process_chunk(vint4 x, vint4 av, int b, int j) {
    // per-lane products and local inclusive prefix
    int p0 = av.x * x.x;
    int p1 = av.y * x.y;
    int p2 = av.z * x.z;
    int p3 = av.w * x.w;
    int l1 = p0 + p1;
    int l2 = l1 + p2;
    int l3 = l2 + p3;   // lane total

    // 16-lane inclusive scan of lane totals (DPP row_shr, zero-fill)
    int v = l3;
    v += dpp_mov<0x111>(v);   // row_shr:1
    v += dpp_mov<0x112>(v);   // row_shr:2
    v += dpp_mov<0x114>(v);   // row_shr:4
    v += dpp_mov<0x118>(v);   // row_shr:8
    int excl = v - l3;

    int pid0 = ((excl + p0 + b) % PRIME) & 65535;
    int pid1 = ((excl + l1 + b) % PRIME) & 65535;
    int pid2 = ((excl + l2 + b) % PRIME) & 65535;
    int pid3 = ((excl + l3 + b) % PRIME) & 65535;

    // row length = count of nonzero digits; row_ror butterfly -> all lanes
    int cnt = (x.x != 0) + (x.y != 0) + (x.z != 0) + (x.w != 0);
    cnt += dpp_mov<0x128>(cnt);   // row_ror:8
    cnt += dpp_mov<0x124>(cnt);   // row_ror:4
    cnt += dpp_mov<0x122>(cnt);   // row_ror:2
    cnt += dpp_mov<0x121>(cnt);   // row_ror:1

    // broadcast prefix_ids[(cnt-1) mod 64]: zero non-owner, add-reduce
    int g     = (cnt == 0) ? 63 : (cnt - 1);   // JAX: (-1) % 64 == 63
    int slot  = g & 3;                          // row-uniform
    int owner = g >> 2;                         // lane-in-group holding it
    int sel   = (slot == 0) ? pid0 : (slot == 1) ? pid1
              : (slot == 2) ? pid2 : pid3;
    int last  = (j == owner) ? sel : 0;
    last += dpp_mov<0x128>(last);
    last += dpp_mov<0x124>(last);
    last += dpp_mov<0x122>(last);
    last += dpp_mov<0x121>(last);

    int base_pos = j << 2;
    vint4 o;
    o.x = (base_pos + 0 < cnt) ? pid0 : last;
    o.y = (base_pos + 1 < cnt) ? pid1 : last;
    o.z = (base_pos + 2 < cnt) ? pid2 : last;
    o.w = (base_pos + 3 < cnt) ? pid3 : last;
    return o;
}

__global__ __launch_bounds__(256) void BaseHashCode_kernel(
    const vint4* __restrict__ seq4,  // [rows*16] vint4 view of [rows][64] int32
    const int*   __restrict__ a,     // [64]
    const int*   __restrict__ bptr,  // [1]
    vint4* __restrict__ out4,        // [rows*16]
    int total_chunks)                // rows*16 (multiple of 256)
{
    const int lane = threadIdx.x & 63;
    const int j    = lane & 15;          // lane within 16-lane row group
    const int b    = bptr[0];
    const vint4 av = reinterpret_cast<const vint4*>(a)[j];  // a[4j..4j+3]

    const int waves_per_block = blockDim.x >> 6;
    const int gwave       = blockIdx.x * waves_per_block + (threadIdx.x >> 6);
    const int total_waves = gridDim.x * waves_per_block;
    const int outer_step  = total_waves * 256;   // chunks consumed per sweep

    // Each wave owns a contiguous 256-chunk (4KB) tile per outer iteration:
    //   chunk(u) = tb + u*64 + lane,  u = 0..3  (4 adjacent 1KB bursts).
    // tb is wave-uniform (scalar loop) and a multiple of 256, so every
    // 16-lane DPP group maps onto whole rows (offsets all multiples of 16).
    for (int tb = gwave << 8; tb < total_chunks; tb += outer_step) {
        const int c = tb + lane;
        vint4 x0 = __builtin_nontemporal_load(&seq4[c]);
        vint4 x1 = __builtin_nontemporal_load(&seq4[c + 64]);
        vint4 x2 = __builtin_nontemporal_load(&seq4[c + 128]);
        vint4 x3 = __builtin_nontemporal_load(&seq4[c + 192]);
        vint4 o0 = process_chunk(x0, av, b, j);
        vint4 o1 = process_chunk(x1, av, b, j);
        vint4 o2 = process_chunk(x2, av, b, j);
        vint4 o3 = process_chunk(x3, av, b, j);
        __builtin_nontemporal_store(o0, &out4[c]);
        __builtin_nontemporal_store(o1, &out4[c + 64]);
        __builtin_nontemporal_store(o2, &out4[c + 128]);
        __builtin_nontemporal_store(o3, &out4[c + 192]);
    }
}

extern "C" void kernel_launch(void* const* d_in, const int* in_sizes, int n_in,
                              void* d_out, int out_size, void* d_ws, size_t ws_size,
                              hipStream_t stream) {
    const vint4* seq4 = reinterpret_cast<const vint4*>(d_in[0]);
    const int*   a    = reinterpret_cast<const int*>(d_in[1]);
    const int*   bptr = reinterpret_cast<const int*>(d_in[2]);
    vint4*       out4 = reinterpret_cast<vint4*>(d_out);

    const int total_chunks = in_sizes[0] / 4;   // rows*16 vint4 chunks

    const int threads = 256;
    const int blocks  = 2048;   // 8 blocks/CU (max resident); 8 sweeps exactly
    hipLaunchKernelGGL(BaseHashCode_kernel, dim3(blocks), dim3(threads), 0, stream,
                       seq4, a, bptr, out4, total_chunks);
}